// Round 16
// baseline (124.444 us; speedup 1.0000x reference)
//
#include <hip/hip_runtime.h>
#include <hip/hip_bf16.h>

#define BB 2
#define TT 2048
#define CC 1024
#define NHEAD 16
#define DHEAD 64
#define MM (BB*TT)
#define KVB 128

using bf16 = __hip_bfloat16;
typedef __bf16 bf16x8 __attribute__((ext_vector_type(8)));
typedef __bf16 bf16x4 __attribute__((ext_vector_type(4)));
typedef float f32x4 __attribute__((ext_vector_type(4)));

static __device__ __forceinline__ bf16 f2b(float f) { return __float2bfloat16(f); }
static __device__ __forceinline__ float fast_exp2(float f) { return __builtin_amdgcn_exp2f(f); }

// async global -> LDS, 16B per lane (dest wave-uniform base; HW adds lane*16B)
static __device__ __forceinline__ void gload16(const bf16* g, bf16* l) {
  __builtin_amdgcn_global_load_lds((__attribute__((address_space(1))) const void*)g,
                                   (__attribute__((address_space(3))) void*)l, 16, 0, 0);
}

// ------------- fused prep: x->bf16 convert + Wqkv^T + Wproj^T -------------
__global__ __launch_bounds__(256)
void k_prep(const float* __restrict__ x, bf16* __restrict__ Xb,
            const float* __restrict__ Wqkv, bf16* __restrict__ WqkvT,
            const float* __restrict__ Wproj, bf16* __restrict__ WprojT)
{
  int bid = blockIdx.x;
  const int tid = threadIdx.x;
  if (bid < 1024) {
    int base = bid * 1024 + tid;
#pragma unroll
    for (int k = 0; k < 4; ++k) {
      int i = base + k * 256;
      float4 v = reinterpret_cast<const float4*>(x)[i];
      bf16 o[4] = { f2b(v.x), f2b(v.y), f2b(v.z), f2b(v.w) };
      reinterpret_cast<uint2*>(Xb)[i] = *reinterpret_cast<uint2*>(o);
    }
    return;
  }
  bid -= 1024;
  __shared__ float tile[32][33];
  const float* W; bf16* WT; int R, Cc, bx, by;
  if (bid < 3072) {
    W = Wqkv;  WT = WqkvT;  R = CC; Cc = 3*CC;
    bx = bid % 96; by = bid / 96;
  } else {
    bid -= 3072;
    W = Wproj; WT = WprojT; R = CC; Cc = CC;
    bx = bid % 32; by = bid / 32;
  }
  int c0 = bx * 32, r0 = by * 32;
  int tx = tid & 31, ty = tid >> 5;
#pragma unroll
  for (int i = 0; i < 4; ++i)
    tile[ty + 8*i][tx] = W[(size_t)(r0 + ty + 8*i) * Cc + c0 + tx];
  __syncthreads();
#pragma unroll
  for (int i = 0; i < 4; ++i)
    WT[(size_t)(c0 + ty + 8*i) * R + r0 + tx] = f2b(tile[tx][ty + 8*i]);
}

// ------------- per-head V (T x D) -> V^T (D x T), bf16 -------------
__global__ void k_vtrans(const bf16* __restrict__ V, bf16* __restrict__ VT) {
  __shared__ bf16 tile[32][33];
  const int bn = blockIdx.z;
  const int d0 = blockIdx.x * 32, t0 = blockIdx.y * 32;
  const size_t base = (size_t)bn * TT * DHEAD;
  int tx = threadIdx.x, ty = threadIdx.y;
#pragma unroll
  for (int i = 0; i < 4; ++i)
    tile[ty + 8*i][tx] = V[base + (size_t)(t0 + ty + 8*i) * DHEAD + d0 + tx];
  __syncthreads();
#pragma unroll
  for (int i = 0; i < 4; ++i)
    VT[base + (size_t)(d0 + ty + 8*i) * TT + t0 + tx] = tile[tx][ty + 8*i];
}

// ============ QKV GEMM (R11, unchanged): 128x256, BK=32, 3-deep + counted vmcnt ============
#define NTK 32
__global__ __launch_bounds__(512, 2)
void k_gemm_qkv(const bf16* __restrict__ Ag, const bf16* __restrict__ Bg,
                const float* __restrict__ bias,
                bf16* __restrict__ Qb, bf16* __restrict__ Kb, bf16* __restrict__ Vb)
{
  const int tid = threadIdx.x;
  const int w = tid >> 6, l = tid & 63;
  const int l16 = l & 15, l4 = l >> 4;
  const int wr = w >> 2, wc = w & 3;

  const int flat = blockIdx.x;
  const int xcd = flat & 7, local = flat >> 3;
  const int bx = (xcd & 1) * 6 + local % 6;
  const int by = (xcd >> 1) * 8 + local / 6;
  const int m0 = by * 128, n0 = bx * 256;

  __shared__ __align__(16) bf16 sm[36864];

  f32x4 acc[4][4];
#pragma unroll
  for (int m = 0; m < 4; ++m)
#pragma unroll
    for (int n = 0; n < 4; ++n) acc[m][n] = 0.f;

  const int srow = tid >> 2;
  const int scol = ((tid & 3) ^ ((tid >> 3) & 3)) * 8;

#define STAGE(buf, kt) do {                                                            \
    const int kb = (kt) * 32 + scol;                                                   \
    gload16(&Ag[(size_t)(m0 +       srow) * CC + kb], &sm[(buf)*12288        + w*512]);\
    gload16(&Bg[(size_t)(n0 +       srow) * CC + kb], &sm[(buf)*12288 + 4096 + w*512]);\
    gload16(&Bg[(size_t)(n0 + 128 + srow) * CC + kb], &sm[(buf)*12288 + 8192 + w*512]);\
  } while (0)

  STAGE(0, 0);
  STAGE(1, 1);
  STAGE(2, 2);
  asm volatile("s_waitcnt vmcnt(6)" ::: "memory");
  __builtin_amdgcn_s_barrier();

  const int slotA = (l4 ^ ((l16 >> 1) & 3)) * 8;
  const int aoff = wr * 2048 + l16 * 32 + slotA;
  const int boff = 4096 + wc * 2048 + l16 * 32 + slotA;

  int rb = 0;
  for (int kt = 0; kt < NTK; ++kt) {
    const int base = rb * 12288;

    bf16x8 af[4], bfr[4];
#pragma unroll
    for (int m = 0; m < 4; ++m)
      af[m] = *reinterpret_cast<const bf16x8*>(&sm[base + aoff + m*512]);
#pragma unroll
    for (int n = 0; n < 4; ++n)
      bfr[n] = *reinterpret_cast<const bf16x8*>(&sm[base + boff + n*512]);
    __builtin_amdgcn_s_setprio(1);
#pragma unroll
    for (int m = 0; m < 4; ++m)
#pragma unroll
      for (int n = 0; n < 4; ++n)
        acc[m][n] = __builtin_amdgcn_mfma_f32_16x16x32_bf16(af[m], bfr[n], acc[m][n], 0, 0, 0);
    __builtin_amdgcn_s_setprio(0);

    __builtin_amdgcn_s_barrier();
    if (kt + 3 < NTK) {
      STAGE(rb, kt + 3);
      asm volatile("s_waitcnt vmcnt(6)" ::: "memory");
    } else if (kt + 2 < NTK) {
      asm volatile("s_waitcnt vmcnt(3)" ::: "memory");
    } else if (kt + 1 < NTK) {
      asm volatile("s_waitcnt vmcnt(0)" ::: "memory");
    }
    __builtin_amdgcn_s_barrier();
    rb = (rb + 1 == 3) ? 0 : rb + 1;
  }
#undef STAGE

  const int ccol = n0 + wc * 64;
  const int which = ccol >> 10;
  bf16* __restrict__ dst = (which == 0) ? Qb : (which == 1) ? Kb : Vb;
  const float qsc = (which == 0) ? 0.125f * 1.4426950408889634f : 1.0f;
#pragma unroll
  for (int m = 0; m < 4; ++m)
#pragma unroll
    for (int n = 0; n < 4; ++n) {
      int gc = ccol + n*16 + l16;
      float bv = bias[gc];
      int c = gc & (CC-1), head = c >> 6, d = c & 63;
#pragma unroll
      for (int j = 0; j < 4; ++j) {
        int gr = m0 + wr*64 + m*16 + l4*4 + j;
        int b = gr >> 11, t = gr & (TT-1);
        dst[(((size_t)b*NHEAD + head)*TT + t)*DHEAD + d] = f2b((acc[m][n][j] + bv) * qsc);
      }
    }
}

// ============ proj GEMM (R13, unchanged): 128x128, 512 thr, 3-deep + counted vmcnt ============
__global__ __launch_bounds__(512, 1)
void k_gemm_proj(const bf16* __restrict__ Ag, const bf16* __restrict__ Bg,
                 const float* __restrict__ bias, float* __restrict__ outF)
{
  const int tid = threadIdx.x;
  const int w = tid >> 6, l = tid & 63;
  const int l16 = l & 15, l4 = l >> 4;
  const int wr = w >> 2, wc = w & 3;

  const int flat = blockIdx.x;
  const int swz = (flat & 7) * 32 + (flat >> 3);
  const int bx = swz >> 5, by = swz & 31;
  const int m0 = by * 128, n0 = bx * 128;

  __shared__ __align__(16) bf16 sm[24576];

  f32x4 acc[4][2];
#pragma unroll
  for (int m = 0; m < 4; ++m)
#pragma unroll
    for (int n = 0; n < 2; ++n) acc[m][n] = 0.f;

  const int srow = tid >> 2;
  const int scol = ((tid & 3) ^ ((tid >> 3) & 3)) * 8;

#define STAGE(buf, kt) do {                                                            \
    const int kb = (kt) * 32 + scol;                                                   \
    gload16(&Ag[(size_t)(m0 + srow) * CC + kb], &sm[(buf)*8192        + w*512]);       \
    gload16(&Bg[(size_t)(n0 + srow) * CC + kb], &sm[(buf)*8192 + 4096 + w*512]);       \
  } while (0)

  STAGE(0, 0);
  STAGE(1, 1);
  STAGE(2, 2);
  asm volatile("s_waitcnt vmcnt(4)" ::: "memory");
  __builtin_amdgcn_s_barrier();

  const int slotA = (l4 ^ ((l16 >> 1) & 3)) * 8;
  const int aoff = wr * 2048 + l16 * 32 + slotA;
  const int boff = 4096 + wc * 1024 + l16 * 32 + slotA;

  int rb = 0;
  for (int kt = 0; kt < NTK; ++kt) {
    const int base = rb * 8192;

    bf16x8 af[4], bfr[2];
#pragma unroll
    for (int m = 0; m < 4; ++m)
      af[m] = *reinterpret_cast<const bf16x8*>(&sm[base + aoff + m*512]);
#pragma unroll
    for (int n = 0; n < 2; ++n)
      bfr[n] = *reinterpret_cast<const bf16x8*>(&sm[base + boff + n*512]);
    __builtin_amdgcn_s_setprio(1);
#pragma unroll
    for (int m = 0; m < 4; ++m)
#pragma unroll
      for (int n = 0; n < 2; ++n)
        acc[m][n] = __builtin_amdgcn_mfma_f32_16x16x32_bf16(af[m], bfr[n], acc[m][n], 0, 0, 0);
    __builtin_amdgcn_s_setprio(0);

    __builtin_amdgcn_s_barrier();
    if (kt + 3 < NTK) {
      STAGE(rb, kt + 3);
      asm volatile("s_waitcnt vmcnt(4)" ::: "memory");
    } else if (kt + 2 < NTK) {
      asm volatile("s_waitcnt vmcnt(2)" ::: "memory");
    } else if (kt + 1 < NTK) {
      asm volatile("s_waitcnt vmcnt(0)" ::: "memory");
    }
    __builtin_amdgcn_s_barrier();
    rb = (rb + 1 == 3) ? 0 : rb + 1;
  }
#undef STAGE

#pragma unroll
  for (int m = 0; m < 4; ++m)
#pragma unroll
    for (int n = 0; n < 2; ++n) {
      int gc = n0 + wc*32 + n*16 + l16;
      float bv = bias[gc];
#pragma unroll
      for (int j = 0; j < 4; ++j) {
        int gr = m0 + wr*64 + m*16 + l4*4 + j;
        outF[(size_t)gr * CC + gc] = acc[m][n][j] + bv;
      }
    }
}

// ---- softmax helper (per 16-row q-frag); static indexing preserved via inlined refs ----
static __device__ __forceinline__ void softmax_frag(
    f32x4 (&s)[8], f32x4 (&o)[4], float &mrun, float &lrun,
    bf16* __restrict__ PlRow, int lane, int l16, int l4)
{
  float mx[8];
#pragma unroll
  for (int n = 0; n < 8; ++n)
    mx[n] = fmaxf(fmaxf(s[n][0], s[n][1]), fmaxf(s[n][2], s[n][3]));
  float m01 = fmaxf(mx[0], mx[1]), m23 = fmaxf(mx[2], mx[3]);
  float m45 = fmaxf(mx[4], mx[5]), m67 = fmaxf(mx[6], mx[7]);
  float pm = fmaxf(fmaxf(m01, m23), fmaxf(m45, m67));
  pm = fmaxf(pm, __shfl_xor(pm, 16, 64));
  pm = fmaxf(pm, __shfl_xor(pm, 32, 64));

  if (!__all(pm <= mrun + 8.f)) {
    float mn = fmaxf(mrun, pm);
    float corr = fast_exp2(mrun - mn);
    mrun = mn;
    lrun *= corr;
    float cj[4];
#pragma unroll
    for (int j = 0; j < 4; ++j)
      cj[j] = __shfl(corr, ((lane >> 4) << 2) + j, 64);
#pragma unroll
    for (int n = 0; n < 4; ++n)
#pragma unroll
      for (int j = 0; j < 4; ++j) o[n][j] *= cj[j];
  }

  float ps[4] = {0.f, 0.f, 0.f, 0.f};
#pragma unroll
  for (int n = 0; n < 8; ++n) {
    bf16x4 pk;
#pragma unroll
    for (int j = 0; j < 4; ++j) {
      float pv = fast_exp2(s[n][j] - mrun);
      ps[j] += pv;
      pk[j] = (__bf16)pv;
    }
    *reinterpret_cast<bf16x4*>(
        &PlRow[((2*n + (l4 >> 1)) ^ (l16 & 7))*8 + (l4 & 1)*4]) = pk;
  }
  float psum = (ps[0] + ps[1]) + (ps[2] + ps[3]);
  psum += __shfl_xor(psum, 16, 64);
  psum += __shfl_xor(psum, 32, 64);
  lrun += psum;
}

// ---------------- flash attention v12: 32 q-rows/wave (2 frags) — halves K/V LDS reads ----------------
// 4 waves x 32q = 128q block, grid 512, LDS 64KB (2 blocks/CU, 8 waves/CU).
// Each K-frag read feeds 2 QK MFMAs (s0,s1); each V-frag read feeds 2 PV MFMAs (o0,o1).
__global__ __launch_bounds__(256, 2)
void k_attn(const bf16* __restrict__ Qg, const bf16* __restrict__ Kg,
            const bf16* __restrict__ VTg, bf16* __restrict__ Aout)
{
  const int tid  = threadIdx.x;
  const int wave = tid >> 6, lane = tid & 63;
  const int l16 = lane & 15, l4 = lane >> 4;

  const int flat = blockIdx.x;               // 0..511; 8 XCDs x 64, 4 heads/XCD
  const int xcd = flat & 7, i6 = flat >> 3;
  const int bn = xcd*4 + (i6 >> 4);
  const int q0 = (i6 & 15) * 128;
  const int b = bn >> 4, h = bn & (NHEAD-1);

  __shared__ __align__(16) bf16 KsF[128*64];     // 16 KB
  __shared__ __align__(16) bf16 VtF[64*128];     // 16 KB
  __shared__ __align__(16) bf16 PlF[4*32*128];   // 32 KB (per-wave 32 x 128)

  const size_t hb = (size_t)bn * TT * DHEAD;
  const bf16* __restrict__ Kbase = Kg + hb;
  const bf16* __restrict__ Vbase = VTg + hb;

  const int qbase = q0 + wave*32;
  bf16x8 qf[2][2];
#pragma unroll
  for (int f = 0; f < 2; ++f)
#pragma unroll
    for (int kk = 0; kk < 2; ++kk)
      qf[f][kk] = *reinterpret_cast<const bf16x8*>(
          &Qg[hb + (size_t)(qbase + f*16 + l16) * DHEAD + kk*32 + l4*8]);

  f32x4 o0[4], o1[4];
#pragma unroll
  for (int n = 0; n < 4; ++n) { o0[n] = 0.f; o1[n] = 0.f; }
  float mrun0 = -1e30f, lrun0 = 0.f;
  float mrun1 = -1e30f, lrun1 = 0.f;

  // staging: K 128x64 (2 thr/row, 4 slots each), V^T 64x128 (4 thr/row, 4 slots each)
  const int krow = tid >> 1, kq = tid & 1;
  const int vrow = tid >> 2, vq = tid & 3;

  bf16x8 kreg[4], vreg[4];
#pragma unroll
  for (int i = 0; i < 4; ++i) {
    kreg[i] = *reinterpret_cast<const bf16x8*>(&Kbase[(size_t)krow * DHEAD + kq*32 + 8*i]);
    vreg[i] = *reinterpret_cast<const bf16x8*>(&Vbase[(size_t)vrow * TT + vq*32 + 8*i]);
  }
#pragma unroll
  for (int i = 0; i < 4; ++i) {
    *reinterpret_cast<bf16x8*>(&KsF[krow*64 + ((kq*4 + i) ^ (krow & 7))*8]) = kreg[i];
    *reinterpret_cast<bf16x8*>(&VtF[vrow*128 + ((vq*4 + i) ^ (vrow & 7))*8]) = vreg[i];
  }

  bf16* PlW = &PlF[wave * 4096];

  for (int t0 = 0; t0 < TT; t0 += KVB) {
    __syncthreads();                      // staged tile visible
    const bool more = (t0 + KVB < TT);
    if (more) {                           // T14: issue next-tile loads now, commit later
#pragma unroll
      for (int i = 0; i < 4; ++i) {
        kreg[i] = *reinterpret_cast<const bf16x8*>(
            &Kbase[(size_t)(t0 + KVB + krow) * DHEAD + kq*32 + 8*i]);
        vreg[i] = *reinterpret_cast<const bf16x8*>(
            &Vbase[(size_t)vrow * TT + t0 + KVB + vq*32 + 8*i]);
      }
    }

    // S^T = K Q^T for both q-frags; K reads SHARED (each feeds 2 MFMAs)
    f32x4 s0[8], s1[8];
#pragma unroll
    for (int n = 0; n < 8; ++n) { s0[n] = 0.f; s1[n] = 0.f; }
    __builtin_amdgcn_s_setprio(1);
#pragma unroll
    for (int n = 0; n < 8; ++n) {
      bf16x8 kf0 = *reinterpret_cast<const bf16x8*>(
          &KsF[(n*16 + l16)*64 + ((l4    ) ^ (l16 & 7))*8]);
      bf16x8 kf1 = *reinterpret_cast<const bf16x8*>(
          &KsF[(n*16 + l16)*64 + ((4 + l4) ^ (l16 & 7))*8]);
      s0[n] = __builtin_amdgcn_mfma_f32_16x16x32_bf16(kf0, qf[0][0], s0[n], 0, 0, 0);
      s0[n] = __builtin_amdgcn_mfma_f32_16x16x32_bf16(kf1, qf[0][1], s0[n], 0, 0, 0);
      s1[n] = __builtin_amdgcn_mfma_f32_16x16x32_bf16(kf0, qf[1][0], s1[n], 0, 0, 0);
      s1[n] = __builtin_amdgcn_mfma_f32_16x16x32_bf16(kf1, qf[1][1], s1[n], 0, 0, 0);
    }
    __builtin_amdgcn_s_setprio(0);

    // online softmax per frag (exp2 domain, defer-max, tree reductions)
    softmax_frag(s0, o0, mrun0, lrun0, &PlW[(l16     )*128], lane, l16, l4);
    softmax_frag(s1, o1, mrun1, lrun1, &PlW[(16 + l16)*128], lane, l16, l4);

    // O += P V for both frags; V reads SHARED (each feeds 2 MFMAs)
    bf16x8 pf0[4], pf1[4];
#pragma unroll
    for (int kk = 0; kk < 4; ++kk) {
      pf0[kk] = *reinterpret_cast<const bf16x8*>(
          &PlW[(l16     )*128 + ((4*kk + l4) ^ (l16 & 7))*8]);
      pf1[kk] = *reinterpret_cast<const bf16x8*>(
          &PlW[(16 + l16)*128 + ((4*kk + l4) ^ (l16 & 7))*8]);
    }
    __builtin_amdgcn_s_setprio(1);
#pragma unroll
    for (int n = 0; n < 4; ++n)
#pragma unroll
      for (int kk = 0; kk < 4; ++kk) {
        bf16x8 vf = *reinterpret_cast<const bf16x8*>(
            &VtF[(n*16 + l16)*128 + ((4*kk + l4) ^ (l16 & 7))*8]);
        o0[n] = __builtin_amdgcn_mfma_f32_16x16x32_bf16(pf0[kk], vf, o0[n], 0, 0, 0);
        o1[n] = __builtin_amdgcn_mfma_f32_16x16x32_bf16(pf1[kk], vf, o1[n], 0, 0, 0);
      }
    __builtin_amdgcn_s_setprio(0);

    __syncthreads();                      // all waves done reading Ks/Vt
    if (more) {
#pragma unroll
      for (int i = 0; i < 4; ++i) {
        *reinterpret_cast<bf16x8*>(&KsF[krow*64 + ((kq*4 + i) ^ (krow & 7))*8]) = kreg[i];
        *reinterpret_cast<bf16x8*>(&VtF[vrow*128 + ((vq*4 + i) ^ (vrow & 7))*8]) = vreg[i];
      }
    }
  }

  // epilogue (per frag)
  {
    float linv = 1.0f / lrun0;
    float lj[4];
#pragma unroll
    for (int j = 0; j < 4; ++j)
      lj[j] = __shfl(linv, ((lane >> 4) << 2) + j, 64);
#pragma unroll
    for (int j = 0; j < 4; ++j) {
      int gt = qbase + l4*4 + j;
#pragma unroll
      for (int n = 0; n < 4; ++n)
        Aout[((size_t)(b*TT + gt))*CC + h*DHEAD + n*16 + l16] = f2b(o0[n][j] * lj[j]);
    }
  }
  {
    float linv = 1.0f / lrun1;
    float lj[4];
#pragma unroll
    for (int j = 0; j < 4; ++j)
      lj[j] = __shfl(linv, ((lane >> 4) << 2) + j, 64);
#pragma unroll
    for (int j = 0; j < 4; ++j) {
      int gt = qbase + 16 + l4*4 + j;
#pragma unroll
      for (int n = 0; n < 4; ++n)
        Aout[((size_t)(b*TT + gt))*CC + h*DHEAD + n*16 + l16] = f2b(o1[n][j] * lj[j]);
    }
  }
}

extern "C" void kernel_launch(void* const* d_in, const int* in_sizes, int n_in,
                              void* d_out, int out_size, void* d_ws, size_t ws_size,
                              hipStream_t stream)
{
  const float* x     = (const float*)d_in[0];
  const float* Wqkv  = (const float*)d_in[1];
  const float* bqkv  = (const float*)d_in[2];
  const float* Wproj = (const float*)d_in[3];
  const float* bproj = (const float*)d_in[4];
  float* out = (float*)d_out;

  char* p = (char*)d_ws;
  bf16* Xb     = (bf16*)p;  p += (size_t)MM*CC*2;
  bf16* WqkvT  = (bf16*)p;  p += (size_t)3*CC*CC*2;
  bf16* WprojT = (bf16*)p;  p += (size_t)CC*CC*2;
  bf16* Qb     = (bf16*)p;  p += (size_t)MM*CC*2;
  bf16* Kb     = (bf16*)p;  p += (size_t)MM*CC*2;
  bf16* Vb     = (bf16*)p;  p += (size_t)MM*CC*2;
  bf16* Attn   = (bf16*)p;  p += (size_t)MM*CC*2;
  bf16* VTb    = Xb;

  k_prep<<<5120, 256, 0, stream>>>(x, Xb, Wqkv, WqkvT, Wproj, WprojT);
  k_gemm_qkv<<<384, 512, 0, stream>>>(Xb, WqkvT, bqkv, Qb, Kb, Vb);
  k_vtrans<<<dim3(DHEAD/32, TT/32, BB*NHEAD), dim3(32, 8), 0, stream>>>(Vb, VTb);
  k_attn<<<512, 256, 0, stream>>>(Qb, Kb, VTb, Attn);
  k_gemm_proj<<<256, 512, 0, stream>>>(Attn, WprojT, bproj, out);
}

// Round 17
// 120.063 us; speedup vs baseline: 1.0365x; 1.0365x over previous
//
#include <hip/hip_runtime.h>
#include <hip/hip_bf16.h>

#define BB 2
#define TT 2048
#define CC 1024
#define NHEAD 16
#define DHEAD 64
#define MM (BB*TT)
#define KVB 128

using bf16 = __hip_bfloat16;
typedef __bf16 bf16x8 __attribute__((ext_vector_type(8)));
typedef __bf16 bf16x4 __attribute__((ext_vector_type(4)));
typedef float f32x4 __attribute__((ext_vector_type(4)));

static __device__ __forceinline__ bf16 f2b(float f) { return __float2bfloat16(f); }
static __device__ __forceinline__ float fast_exp2(float f) { return __builtin_amdgcn_exp2f(f); }

// async global -> LDS, 16B per lane (dest wave-uniform base; HW adds lane*16B)
static __device__ __forceinline__ void gload16(const bf16* g, bf16* l) {
  __builtin_amdgcn_global_load_lds((__attribute__((address_space(1))) const void*)g,
                                   (__attribute__((address_space(3))) void*)l, 16, 0, 0);
}

// ------------- fused prep: x->bf16 convert + Wqkv^T + Wproj^T -------------
__global__ __launch_bounds__(256)
void k_prep(const float* __restrict__ x, bf16* __restrict__ Xb,
            const float* __restrict__ Wqkv, bf16* __restrict__ WqkvT,
            const float* __restrict__ Wproj, bf16* __restrict__ WprojT)
{
  int bid = blockIdx.x;
  const int tid = threadIdx.x;
  if (bid < 1024) {
    int base = bid * 1024 + tid;
#pragma unroll
    for (int k = 0; k < 4; ++k) {
      int i = base + k * 256;
      float4 v = reinterpret_cast<const float4*>(x)[i];
      bf16 o[4] = { f2b(v.x), f2b(v.y), f2b(v.z), f2b(v.w) };
      reinterpret_cast<uint2*>(Xb)[i] = *reinterpret_cast<uint2*>(o);
    }
    return;
  }
  bid -= 1024;
  __shared__ float tile[32][33];
  const float* W; bf16* WT; int R, Cc, bx, by;
  if (bid < 3072) {
    W = Wqkv;  WT = WqkvT;  R = CC; Cc = 3*CC;
    bx = bid % 96; by = bid / 96;
  } else {
    bid -= 3072;
    W = Wproj; WT = WprojT; R = CC; Cc = CC;
    bx = bid % 32; by = bid / 32;
  }
  int c0 = bx * 32, r0 = by * 32;
  int tx = tid & 31, ty = tid >> 5;
#pragma unroll
  for (int i = 0; i < 4; ++i)
    tile[ty + 8*i][tx] = W[(size_t)(r0 + ty + 8*i) * Cc + c0 + tx];
  __syncthreads();
#pragma unroll
  for (int i = 0; i < 4; ++i)
    WT[(size_t)(c0 + ty + 8*i) * R + r0 + tx] = f2b(tile[tx][ty + 8*i]);
}

// ============ QKV GEMM: 128x256, BK=32, 3-deep + counted vmcnt ============
// Epilogue: Q,K -> (B,N,T,D) scatter (Q pre-scaled by log2e/8); V -> (B,N,D,T)
// TRANSPOSED directly (replaces the old k_vtrans kernel).
#define NTK 32
__global__ __launch_bounds__(512, 2)
void k_gemm_qkv(const bf16* __restrict__ Ag, const bf16* __restrict__ Bg,
                const float* __restrict__ bias,
                bf16* __restrict__ Qb, bf16* __restrict__ Kb, bf16* __restrict__ Vb)
{
  const int tid = threadIdx.x;
  const int w = tid >> 6, l = tid & 63;
  const int l16 = l & 15, l4 = l >> 4;
  const int wr = w >> 2, wc = w & 3;

  const int flat = blockIdx.x;
  const int xcd = flat & 7, local = flat >> 3;
  const int bx = (xcd & 1) * 6 + local % 6;
  const int by = (xcd >> 1) * 8 + local / 6;
  const int m0 = by * 128, n0 = bx * 256;

  __shared__ __align__(16) bf16 sm[36864];

  f32x4 acc[4][4];
#pragma unroll
  for (int m = 0; m < 4; ++m)
#pragma unroll
    for (int n = 0; n < 4; ++n) acc[m][n] = 0.f;

  const int srow = tid >> 2;
  const int scol = ((tid & 3) ^ ((tid >> 3) & 3)) * 8;

#define STAGE(buf, kt) do {                                                            \
    const int kb = (kt) * 32 + scol;                                                   \
    gload16(&Ag[(size_t)(m0 +       srow) * CC + kb], &sm[(buf)*12288        + w*512]);\
    gload16(&Bg[(size_t)(n0 +       srow) * CC + kb], &sm[(buf)*12288 + 4096 + w*512]);\
    gload16(&Bg[(size_t)(n0 + 128 + srow) * CC + kb], &sm[(buf)*12288 + 8192 + w*512]);\
  } while (0)

  STAGE(0, 0);
  STAGE(1, 1);
  STAGE(2, 2);
  asm volatile("s_waitcnt vmcnt(6)" ::: "memory");
  __builtin_amdgcn_s_barrier();

  const int slotA = (l4 ^ ((l16 >> 1) & 3)) * 8;
  const int aoff = wr * 2048 + l16 * 32 + slotA;
  const int boff = 4096 + wc * 2048 + l16 * 32 + slotA;

  int rb = 0;
  for (int kt = 0; kt < NTK; ++kt) {
    const int base = rb * 12288;

    bf16x8 af[4], bfr[4];
#pragma unroll
    for (int m = 0; m < 4; ++m)
      af[m] = *reinterpret_cast<const bf16x8*>(&sm[base + aoff + m*512]);
#pragma unroll
    for (int n = 0; n < 4; ++n)
      bfr[n] = *reinterpret_cast<const bf16x8*>(&sm[base + boff + n*512]);
    __builtin_amdgcn_s_setprio(1);
#pragma unroll
    for (int m = 0; m < 4; ++m)
#pragma unroll
      for (int n = 0; n < 4; ++n)
        acc[m][n] = __builtin_amdgcn_mfma_f32_16x16x32_bf16(af[m], bfr[n], acc[m][n], 0, 0, 0);
    __builtin_amdgcn_s_setprio(0);

    __builtin_amdgcn_s_barrier();
    if (kt + 3 < NTK) {
      STAGE(rb, kt + 3);
      asm volatile("s_waitcnt vmcnt(6)" ::: "memory");
    } else if (kt + 2 < NTK) {
      asm volatile("s_waitcnt vmcnt(3)" ::: "memory");
    } else if (kt + 1 < NTK) {
      asm volatile("s_waitcnt vmcnt(0)" ::: "memory");
    }
    __builtin_amdgcn_s_barrier();
    rb = (rb + 1 == 3) ? 0 : rb + 1;
  }
#undef STAGE

  const int ccol = n0 + wc * 64;
  const int which = ccol >> 10;              // uniform per wave
  if (which == 2) {
    // V third: write transposed (B,N,D,T); j-values are 4 consecutive t -> 8B store
#pragma unroll
    for (int m = 0; m < 4; ++m)
#pragma unroll
      for (int n = 0; n < 4; ++n) {
        int gc = ccol + n*16 + l16;
        float bv = bias[gc];
        int c = gc & (CC-1), head = c >> 6, d = c & 63;
        int t0r = m0 + wr*64 + m*16 + l4*4;
        int b = t0r >> 11, t = t0r & (TT-1);
        bf16x4 pk;
#pragma unroll
        for (int j = 0; j < 4; ++j) pk[j] = (__bf16)(acc[m][n][j] + bv);
        *reinterpret_cast<bf16x4*>(
            &Vb[(((size_t)b*NHEAD + head)*DHEAD + d)*TT + t]) = pk;
      }
  } else {
    bf16* __restrict__ dst = (which == 0) ? Qb : Kb;
    const float qsc = (which == 0) ? 0.125f * 1.4426950408889634f : 1.0f;
#pragma unroll
    for (int m = 0; m < 4; ++m)
#pragma unroll
      for (int n = 0; n < 4; ++n) {
        int gc = ccol + n*16 + l16;
        float bv = bias[gc];
        int c = gc & (CC-1), head = c >> 6, d = c & 63;
#pragma unroll
        for (int j = 0; j < 4; ++j) {
          int gr = m0 + wr*64 + m*16 + l4*4 + j;
          int b = gr >> 11, t = gr & (TT-1);
          dst[(((size_t)b*NHEAD + head)*TT + t)*DHEAD + d] = f2b((acc[m][n][j] + bv) * qsc);
        }
      }
  }
}

// ============ proj GEMM (R13, unchanged): 128x128, 512 thr, 3-deep + counted vmcnt ============
__global__ __launch_bounds__(512, 1)
void k_gemm_proj(const bf16* __restrict__ Ag, const bf16* __restrict__ Bg,
                 const float* __restrict__ bias, float* __restrict__ outF)
{
  const int tid = threadIdx.x;
  const int w = tid >> 6, l = tid & 63;
  const int l16 = l & 15, l4 = l >> 4;
  const int wr = w >> 2, wc = w & 3;

  const int flat = blockIdx.x;
  const int swz = (flat & 7) * 32 + (flat >> 3);
  const int bx = swz >> 5, by = swz & 31;
  const int m0 = by * 128, n0 = bx * 128;

  __shared__ __align__(16) bf16 sm[24576];

  f32x4 acc[4][2];
#pragma unroll
  for (int m = 0; m < 4; ++m)
#pragma unroll
    for (int n = 0; n < 2; ++n) acc[m][n] = 0.f;

  const int srow = tid >> 2;
  const int scol = ((tid & 3) ^ ((tid >> 3) & 3)) * 8;

#define STAGE(buf, kt) do {                                                            \
    const int kb = (kt) * 32 + scol;                                                   \
    gload16(&Ag[(size_t)(m0 + srow) * CC + kb], &sm[(buf)*8192        + w*512]);       \
    gload16(&Bg[(size_t)(n0 + srow) * CC + kb], &sm[(buf)*8192 + 4096 + w*512]);       \
  } while (0)

  STAGE(0, 0);
  STAGE(1, 1);
  STAGE(2, 2);
  asm volatile("s_waitcnt vmcnt(4)" ::: "memory");
  __builtin_amdgcn_s_barrier();

  const int slotA = (l4 ^ ((l16 >> 1) & 3)) * 8;
  const int aoff = wr * 2048 + l16 * 32 + slotA;
  const int boff = 4096 + wc * 1024 + l16 * 32 + slotA;

  int rb = 0;
  for (int kt = 0; kt < NTK; ++kt) {
    const int base = rb * 8192;

    bf16x8 af[4], bfr[2];
#pragma unroll
    for (int m = 0; m < 4; ++m)
      af[m] = *reinterpret_cast<const bf16x8*>(&sm[base + aoff + m*512]);
#pragma unroll
    for (int n = 0; n < 2; ++n)
      bfr[n] = *reinterpret_cast<const bf16x8*>(&sm[base + boff + n*512]);
    __builtin_amdgcn_s_setprio(1);
#pragma unroll
    for (int m = 0; m < 4; ++m)
#pragma unroll
      for (int n = 0; n < 2; ++n)
        acc[m][n] = __builtin_amdgcn_mfma_f32_16x16x32_bf16(af[m], bfr[n], acc[m][n], 0, 0, 0);
    __builtin_amdgcn_s_setprio(0);

    __builtin_amdgcn_s_barrier();
    if (kt + 3 < NTK) {
      STAGE(rb, kt + 3);
      asm volatile("s_waitcnt vmcnt(4)" ::: "memory");
    } else if (kt + 2 < NTK) {
      asm volatile("s_waitcnt vmcnt(2)" ::: "memory");
    } else if (kt + 1 < NTK) {
      asm volatile("s_waitcnt vmcnt(0)" ::: "memory");
    }
    __builtin_amdgcn_s_barrier();
    rb = (rb + 1 == 3) ? 0 : rb + 1;
  }
#undef STAGE

#pragma unroll
  for (int m = 0; m < 4; ++m)
#pragma unroll
    for (int n = 0; n < 2; ++n) {
      int gc = n0 + wc*32 + n*16 + l16;
      float bv = bias[gc];
#pragma unroll
      for (int j = 0; j < 4; ++j) {
        int gr = m0 + wr*64 + m*16 + l4*4 + j;
        outF[(size_t)gr * CC + gc] = acc[m][n][j] + bv;
      }
    }
}

// ---------------- flash attention (R15 form — best measured, 63 µs) ----------------
__global__ __launch_bounds__(512, 2)
void k_attn(const bf16* __restrict__ Qg, const bf16* __restrict__ Kg,
            const bf16* __restrict__ VTg, bf16* __restrict__ Aout)
{
  const int tid  = threadIdx.x;
  const int wave = tid >> 6, lane = tid & 63;
  const int l16 = lane & 15, l4 = lane >> 4;

  const int flat = blockIdx.x;               // 0..511; 8 XCDs x 64, 4 heads/XCD
  const int xcd = flat & 7, i6 = flat >> 3;
  const int bn = xcd*4 + (i6 >> 4);
  const int q0 = (i6 & 15) * 128;
  const int b = bn >> 4, h = bn & (NHEAD-1);

  __shared__ __align__(16) bf16 KsF[128*64];     // 16 KB
  __shared__ __align__(16) bf16 VtF[64*128];     // 16 KB
  __shared__ __align__(16) bf16 PlF[8*16*128];   // 32 KB

  const size_t hb = (size_t)bn * TT * DHEAD;
  const bf16* __restrict__ Kbase = Kg + hb;
  const bf16* __restrict__ Vbase = VTg + hb;

  bf16x8 qf[2];
#pragma unroll
  for (int kk = 0; kk < 2; ++kk)
    qf[kk] = *reinterpret_cast<const bf16x8*>(
        &Qg[hb + (size_t)(q0 + wave*16 + l16) * DHEAD + kk*32 + l4*8]);

  f32x4 o[4];
#pragma unroll
  for (int n = 0; n < 4; ++n) o[n] = 0.f;
  float mrun = -1e30f, lrun = 0.f;

  const int krow = tid >> 2, kq = tid & 3;
  const int vrow = tid >> 3, vq = tid & 7;

  bf16x8 kreg[2], vreg[2];
#pragma unroll
  for (int i = 0; i < 2; ++i) {
    kreg[i] = *reinterpret_cast<const bf16x8*>(&Kbase[(size_t)krow * DHEAD + kq*16 + 8*i]);
    vreg[i] = *reinterpret_cast<const bf16x8*>(&Vbase[(size_t)vrow * TT + vq*16 + 8*i]);
  }
#pragma unroll
  for (int i = 0; i < 2; ++i) {
    *reinterpret_cast<bf16x8*>(&KsF[krow*64 + ((kq*2 + i) ^ (krow & 7))*8]) = kreg[i];
    *reinterpret_cast<bf16x8*>(&VtF[vrow*128 + ((vq*2 + i) ^ (vrow & 7))*8]) = vreg[i];
  }

  bf16* PlW = &PlF[wave * 2048];

  for (int t0 = 0; t0 < TT; t0 += KVB) {
    __syncthreads();                      // staged tile visible
    const bool more = (t0 + KVB < TT);
    if (more) {                           // T14: issue next-tile loads now, commit later
#pragma unroll
      for (int i = 0; i < 2; ++i) {
        kreg[i] = *reinterpret_cast<const bf16x8*>(
            &Kbase[(size_t)(t0 + KVB + krow) * DHEAD + kq*16 + 8*i]);
        vreg[i] = *reinterpret_cast<const bf16x8*>(
            &Vbase[(size_t)vrow * TT + t0 + KVB + vq*16 + 8*i]);
      }
    }

    // S^T = K Q^T : lane holds S^T[kv = n*16 + l4*4 + j][q = l16], n = 0..7
    f32x4 s[8];
#pragma unroll
    for (int n = 0; n < 8; ++n) s[n] = 0.f;
    __builtin_amdgcn_s_setprio(1);
#pragma unroll
    for (int n = 0; n < 8; ++n) {
      bf16x8 kf0 = *reinterpret_cast<const bf16x8*>(
          &KsF[(n*16 + l16)*64 + ((l4    ) ^ (l16 & 7))*8]);
      bf16x8 kf1 = *reinterpret_cast<const bf16x8*>(
          &KsF[(n*16 + l16)*64 + ((4 + l4) ^ (l16 & 7))*8]);
      s[n] = __builtin_amdgcn_mfma_f32_16x16x32_bf16(kf0, qf[0], s[n], 0, 0, 0);
      s[n] = __builtin_amdgcn_mfma_f32_16x16x32_bf16(kf1, qf[1], s[n], 0, 0, 0);
    }
    __builtin_amdgcn_s_setprio(0);

    // --- online softmax (exp2 domain), defer-max THR=8; tree reductions ---
    float mx[8];
#pragma unroll
    for (int n = 0; n < 8; ++n)
      mx[n] = fmaxf(fmaxf(s[n][0], s[n][1]), fmaxf(s[n][2], s[n][3]));
    float m01 = fmaxf(mx[0], mx[1]), m23 = fmaxf(mx[2], mx[3]);
    float m45 = fmaxf(mx[4], mx[5]), m67 = fmaxf(mx[6], mx[7]);
    float pm = fmaxf(fmaxf(m01, m23), fmaxf(m45, m67));
    pm = fmaxf(pm, __shfl_xor(pm, 16, 64));
    pm = fmaxf(pm, __shfl_xor(pm, 32, 64));

    if (!__all(pm <= mrun + 8.f)) {
      float mn = fmaxf(mrun, pm);
      float corr = fast_exp2(mrun - mn);
      mrun = mn;
      lrun *= corr;
      float cj[4];
#pragma unroll
      for (int j = 0; j < 4; ++j)
        cj[j] = __shfl(corr, ((lane >> 4) << 2) + j, 64);
#pragma unroll
      for (int n = 0; n < 4; ++n)
#pragma unroll
        for (int j = 0; j < 4; ++j) o[n][j] *= cj[j];
    }

    float ps[4] = {0.f, 0.f, 0.f, 0.f};
#pragma unroll
    for (int n = 0; n < 8; ++n) {
      bf16x4 pk;
#pragma unroll
      for (int j = 0; j < 4; ++j) {
        float pv = fast_exp2(s[n][j] - mrun);
        ps[j] += pv;
        pk[j] = (__bf16)pv;
      }
      *reinterpret_cast<bf16x4*>(
          &PlW[l16*128 + ((2*n + (l4 >> 1)) ^ (l16 & 7))*8 + (l4 & 1)*4]) = pk;
    }
    float psum = (ps[0] + ps[1]) + (ps[2] + ps[3]);
    psum += __shfl_xor(psum, 16, 64);
    psum += __shfl_xor(psum, 32, 64);
    lrun += psum;

    // O += P V : A = P[q][kv] (per-wave LDS), B = V^T[d][kv] (LDS)
    bf16x8 pf[4];
#pragma unroll
    for (int kk = 0; kk < 4; ++kk)
      pf[kk] = *reinterpret_cast<const bf16x8*>(
          &PlW[l16*128 + ((4*kk + l4) ^ (l16 & 7))*8]);
    __builtin_amdgcn_s_setprio(1);
#pragma unroll
    for (int n = 0; n < 4; ++n)
#pragma unroll
      for (int kk = 0; kk < 4; ++kk) {
        bf16x8 vf = *reinterpret_cast<const bf16x8*>(
            &VtF[(n*16 + l16)*128 + ((4*kk + l4) ^ (l16 & 7))*8]);
        o[n] = __builtin_amdgcn_mfma_f32_16x16x32_bf16(pf[kk], vf, o[n], 0, 0, 0);
      }
    __builtin_amdgcn_s_setprio(0);

    __syncthreads();                      // all waves done reading Ks/Vt
    if (more) {
#pragma unroll
      for (int i = 0; i < 2; ++i) {
        *reinterpret_cast<bf16x8*>(&KsF[krow*64 + ((kq*2 + i) ^ (krow & 7))*8]) = kreg[i];
        *reinterpret_cast<bf16x8*>(&VtF[vrow*128 + ((vq*2 + i) ^ (vrow & 7))*8]) = vreg[i];
      }
    }
  }

  // epilogue
  float linv = 1.0f / lrun;
  float lj[4];
#pragma unroll
  for (int j = 0; j < 4; ++j)
    lj[j] = __shfl(linv, ((lane >> 4) << 2) + j, 64);
#pragma unroll
  for (int j = 0; j < 4; ++j) {
    int gt = q0 + wave*16 + l4*4 + j;
#pragma unroll
    for (int n = 0; n < 4; ++n)
      Aout[((size_t)(b*TT + gt))*CC + h*DHEAD + n*16 + l16] = f2b(o[n][j] * lj[j]);
  }
}

extern "C" void kernel_launch(void* const* d_in, const int* in_sizes, int n_in,
                              void* d_out, int out_size, void* d_ws, size_t ws_size,
                              hipStream_t stream)
{
  const float* x     = (const float*)d_in[0];
  const float* Wqkv  = (const float*)d_in[1];
  const float* bqkv  = (const float*)d_in[2];
  const float* Wproj = (const float*)d_in[3];
  const float* bproj = (const float*)d_in[4];
  float* out = (float*)d_out;

  char* p = (char*)d_ws;
  bf16* Xb     = (bf16*)p;  p += (size_t)MM*CC*2;
  bf16* WqkvT  = (bf16*)p;  p += (size_t)3*CC*CC*2;
  bf16* WprojT = (bf16*)p;  p += (size_t)CC*CC*2;
  bf16* Qb     = (bf16*)p;  p += (size_t)MM*CC*2;
  bf16* Kb     = (bf16*)p;  p += (size_t)MM*CC*2;
  bf16* Vb     = (bf16*)p;  p += (size_t)MM*CC*2;   // holds V^T (B,N,D,T) directly
  bf16* Attn   = (bf16*)p;  p += (size_t)MM*CC*2;

  k_prep<<<5120, 256, 0, stream>>>(x, Xb, Wqkv, WqkvT, Wproj, WprojT);
  k_gemm_qkv<<<384, 512, 0, stream>>>(Xb, WqkvT, bqkv, Qb, Kb, Vb);
  k_attn<<<512, 512, 0, stream>>>(Qb, Kb, Vb, Attn);
  k_gemm_proj<<<256, 512, 0, stream>>>(Attn, WprojT, bproj, out);
}

// Round 18
// 118.137 us; speedup vs baseline: 1.0534x; 1.0163x over previous
//
#include <hip/hip_runtime.h>
#include <hip/hip_bf16.h>

#define BB 2
#define TT 2048
#define CC 1024
#define NHEAD 16
#define DHEAD 64
#define MM (BB*TT)
#define KVB 128

using bf16 = __hip_bfloat16;
typedef __bf16 bf16x8 __attribute__((ext_vector_type(8)));
typedef __bf16 bf16x4 __attribute__((ext_vector_type(4)));
typedef float f32x4 __attribute__((ext_vector_type(4)));

static __device__ __forceinline__ bf16 f2b(float f) { return __float2bfloat16(f); }
static __device__ __forceinline__ float fast_exp2(float f) { return __builtin_amdgcn_exp2f(f); }

// async global -> LDS, 16B per lane (dest wave-uniform base; HW adds lane*16B)
static __device__ __forceinline__ void gload16(const bf16* g, bf16* l) {
  __builtin_amdgcn_global_load_lds((__attribute__((address_space(1))) const void*)g,
                                   (__attribute__((address_space(3))) void*)l, 16, 0, 0);
}

// ------------- fused prep: x->bf16 convert + Wqkv^T + Wproj^T -------------
__global__ __launch_bounds__(256)
void k_prep(const float* __restrict__ x, bf16* __restrict__ Xb,
            const float* __restrict__ Wqkv, bf16* __restrict__ WqkvT,
            const float* __restrict__ Wproj, bf16* __restrict__ WprojT)
{
  int bid = blockIdx.x;
  const int tid = threadIdx.x;
  if (bid < 1024) {
    int base = bid * 1024 + tid;
#pragma unroll
    for (int k = 0; k < 4; ++k) {
      int i = base + k * 256;
      float4 v = reinterpret_cast<const float4*>(x)[i];
      bf16 o[4] = { f2b(v.x), f2b(v.y), f2b(v.z), f2b(v.w) };
      reinterpret_cast<uint2*>(Xb)[i] = *reinterpret_cast<uint2*>(o);
    }
    return;
  }
  bid -= 1024;
  __shared__ float tile[32][33];
  const float* W; bf16* WT; int R, Cc, bx, by;
  if (bid < 3072) {
    W = Wqkv;  WT = WqkvT;  R = CC; Cc = 3*CC;
    bx = bid % 96; by = bid / 96;
  } else {
    bid -= 3072;
    W = Wproj; WT = WprojT; R = CC; Cc = CC;
    bx = bid % 32; by = bid / 32;
  }
  int c0 = bx * 32, r0 = by * 32;
  int tx = tid & 31, ty = tid >> 5;
#pragma unroll
  for (int i = 0; i < 4; ++i)
    tile[ty + 8*i][tx] = W[(size_t)(r0 + ty + 8*i) * Cc + c0 + tx];
  __syncthreads();
#pragma unroll
  for (int i = 0; i < 4; ++i)
    WT[(size_t)(c0 + ty + 8*i) * R + r0 + tx] = f2b(tile[tx][ty + 8*i]);
}

// ============ QKV GEMM (R17, unchanged): 128x256, BK=32, 3-deep + counted vmcnt ============
// Epilogue: Q,K -> (B,N,T,D); V -> (B,N,D,T) transposed directly.
#define NTK 32
__global__ __launch_bounds__(512, 2)
void k_gemm_qkv(const bf16* __restrict__ Ag, const bf16* __restrict__ Bg,
                const float* __restrict__ bias,
                bf16* __restrict__ Qb, bf16* __restrict__ Kb, bf16* __restrict__ Vb)
{
  const int tid = threadIdx.x;
  const int w = tid >> 6, l = tid & 63;
  const int l16 = l & 15, l4 = l >> 4;
  const int wr = w >> 2, wc = w & 3;

  const int flat = blockIdx.x;
  const int xcd = flat & 7, local = flat >> 3;
  const int bx = (xcd & 1) * 6 + local % 6;
  const int by = (xcd >> 1) * 8 + local / 6;
  const int m0 = by * 128, n0 = bx * 256;

  __shared__ __align__(16) bf16 sm[36864];

  f32x4 acc[4][4];
#pragma unroll
  for (int m = 0; m < 4; ++m)
#pragma unroll
    for (int n = 0; n < 4; ++n) acc[m][n] = 0.f;

  const int srow = tid >> 2;
  const int scol = ((tid & 3) ^ ((tid >> 3) & 3)) * 8;

#define STAGE(buf, kt) do {                                                            \
    const int kb = (kt) * 32 + scol;                                                   \
    gload16(&Ag[(size_t)(m0 +       srow) * CC + kb], &sm[(buf)*12288        + w*512]);\
    gload16(&Bg[(size_t)(n0 +       srow) * CC + kb], &sm[(buf)*12288 + 4096 + w*512]);\
    gload16(&Bg[(size_t)(n0 + 128 + srow) * CC + kb], &sm[(buf)*12288 + 8192 + w*512]);\
  } while (0)

  STAGE(0, 0);
  STAGE(1, 1);
  STAGE(2, 2);
  asm volatile("s_waitcnt vmcnt(6)" ::: "memory");
  __builtin_amdgcn_s_barrier();

  const int slotA = (l4 ^ ((l16 >> 1) & 3)) * 8;
  const int aoff = wr * 2048 + l16 * 32 + slotA;
  const int boff = 4096 + wc * 2048 + l16 * 32 + slotA;

  int rb = 0;
  for (int kt = 0; kt < NTK; ++kt) {
    const int base = rb * 12288;

    bf16x8 af[4], bfr[4];
#pragma unroll
    for (int m = 0; m < 4; ++m)
      af[m] = *reinterpret_cast<const bf16x8*>(&sm[base + aoff + m*512]);
#pragma unroll
    for (int n = 0; n < 4; ++n)
      bfr[n] = *reinterpret_cast<const bf16x8*>(&sm[base + boff + n*512]);
    __builtin_amdgcn_s_setprio(1);
#pragma unroll
    for (int m = 0; m < 4; ++m)
#pragma unroll
      for (int n = 0; n < 4; ++n)
        acc[m][n] = __builtin_amdgcn_mfma_f32_16x16x32_bf16(af[m], bfr[n], acc[m][n], 0, 0, 0);
    __builtin_amdgcn_s_setprio(0);

    __builtin_amdgcn_s_barrier();
    if (kt + 3 < NTK) {
      STAGE(rb, kt + 3);
      asm volatile("s_waitcnt vmcnt(6)" ::: "memory");
    } else if (kt + 2 < NTK) {
      asm volatile("s_waitcnt vmcnt(3)" ::: "memory");
    } else if (kt + 1 < NTK) {
      asm volatile("s_waitcnt vmcnt(0)" ::: "memory");
    }
    __builtin_amdgcn_s_barrier();
    rb = (rb + 1 == 3) ? 0 : rb + 1;
  }
#undef STAGE

  const int ccol = n0 + wc * 64;
  const int which = ccol >> 10;
  if (which == 2) {
#pragma unroll
    for (int m = 0; m < 4; ++m)
#pragma unroll
      for (int n = 0; n < 4; ++n) {
        int gc = ccol + n*16 + l16;
        float bv = bias[gc];
        int c = gc & (CC-1), head = c >> 6, d = c & 63;
        int t0r = m0 + wr*64 + m*16 + l4*4;
        int b = t0r >> 11, t = t0r & (TT-1);
        bf16x4 pk;
#pragma unroll
        for (int j = 0; j < 4; ++j) pk[j] = (__bf16)(acc[m][n][j] + bv);
        *reinterpret_cast<bf16x4*>(
            &Vb[(((size_t)b*NHEAD + head)*DHEAD + d)*TT + t]) = pk;
      }
  } else {
    bf16* __restrict__ dst = (which == 0) ? Qb : Kb;
    const float qsc = (which == 0) ? 0.125f * 1.4426950408889634f : 1.0f;
#pragma unroll
    for (int m = 0; m < 4; ++m)
#pragma unroll
      for (int n = 0; n < 4; ++n) {
        int gc = ccol + n*16 + l16;
        float bv = bias[gc];
        int c = gc & (CC-1), head = c >> 6, d = c & 63;
#pragma unroll
        for (int j = 0; j < 4; ++j) {
          int gr = m0 + wr*64 + m*16 + l4*4 + j;
          int b = gr >> 11, t = gr & (TT-1);
          dst[(((size_t)b*NHEAD + head)*TT + t)*DHEAD + d] = f2b((acc[m][n][j] + bv) * qsc);
        }
      }
  }
}

// ============ proj GEMM (R13, unchanged): 128x128, 512 thr, 3-deep + counted vmcnt ============
__global__ __launch_bounds__(512, 1)
void k_gemm_proj(const bf16* __restrict__ Ag, const bf16* __restrict__ Bg,
                 const float* __restrict__ bias, float* __restrict__ outF)
{
  const int tid = threadIdx.x;
  const int w = tid >> 6, l = tid & 63;
  const int l16 = l & 15, l4 = l >> 4;
  const int wr = w >> 2, wc = w & 3;

  const int flat = blockIdx.x;
  const int swz = (flat & 7) * 32 + (flat >> 3);
  const int bx = swz >> 5, by = swz & 31;
  const int m0 = by * 128, n0 = bx * 128;

  __shared__ __align__(16) bf16 sm[24576];

  f32x4 acc[4][2];
#pragma unroll
  for (int m = 0; m < 4; ++m)
#pragma unroll
    for (int n = 0; n < 2; ++n) acc[m][n] = 0.f;

  const int srow = tid >> 2;
  const int scol = ((tid & 3) ^ ((tid >> 3) & 3)) * 8;

#define STAGE(buf, kt) do {                                                            \
    const int kb = (kt) * 32 + scol;                                                   \
    gload16(&Ag[(size_t)(m0 + srow) * CC + kb], &sm[(buf)*8192        + w*512]);       \
    gload16(&Bg[(size_t)(n0 + srow) * CC + kb], &sm[(buf)*8192 + 4096 + w*512]);       \
  } while (0)

  STAGE(0, 0);
  STAGE(1, 1);
  STAGE(2, 2);
  asm volatile("s_waitcnt vmcnt(4)" ::: "memory");
  __builtin_amdgcn_s_barrier();

  const int slotA = (l4 ^ ((l16 >> 1) & 3)) * 8;
  const int aoff = wr * 2048 + l16 * 32 + slotA;
  const int boff = 4096 + wc * 1024 + l16 * 32 + slotA;

  int rb = 0;
  for (int kt = 0; kt < NTK; ++kt) {
    const int base = rb * 8192;

    bf16x8 af[4], bfr[2];
#pragma unroll
    for (int m = 0; m < 4; ++m)
      af[m] = *reinterpret_cast<const bf16x8*>(&sm[base + aoff + m*512]);
#pragma unroll
    for (int n = 0; n < 2; ++n)
      bfr[n] = *reinterpret_cast<const bf16x8*>(&sm[base + boff + n*512]);
    __builtin_amdgcn_s_setprio(1);
#pragma unroll
    for (int m = 0; m < 4; ++m)
#pragma unroll
      for (int n = 0; n < 2; ++n)
        acc[m][n] = __builtin_amdgcn_mfma_f32_16x16x32_bf16(af[m], bfr[n], acc[m][n], 0, 0, 0);
    __builtin_amdgcn_s_setprio(0);

    __builtin_amdgcn_s_barrier();
    if (kt + 3 < NTK) {
      STAGE(rb, kt + 3);
      asm volatile("s_waitcnt vmcnt(4)" ::: "memory");
    } else if (kt + 2 < NTK) {
      asm volatile("s_waitcnt vmcnt(2)" ::: "memory");
    } else if (kt + 1 < NTK) {
      asm volatile("s_waitcnt vmcnt(0)" ::: "memory");
    }
    __builtin_amdgcn_s_barrier();
    rb = (rb + 1 == 3) ? 0 : rb + 1;
  }
#undef STAGE

#pragma unroll
  for (int m = 0; m < 4; ++m)
#pragma unroll
    for (int n = 0; n < 2; ++n) {
      int gc = n0 + wc*32 + n*16 + l16;
      float bv = bias[gc];
#pragma unroll
      for (int j = 0; j < 4; ++j) {
        int gr = m0 + wr*64 + m*16 + l4*4 + j;
        outF[(size_t)gr * CC + gc] = acc[m][n][j] + bv;
      }
    }
}

// ---------------- flash attention v13: global_load_lds dbuf staging, 1 barrier/tile ----------------
// K/V double-buffered in LDS via gload16 (linear dest + inverse-swizzled global source);
// Pl halved (PV in two 64-kv halves). LDS = 32+32+16 = 80 KB -> 2 blocks/CU, 16 waves/CU.
__global__ __launch_bounds__(512, 2)
void k_attn(const bf16* __restrict__ Qg, const bf16* __restrict__ Kg,
            const bf16* __restrict__ VTg, bf16* __restrict__ Aout)
{
  const int tid  = threadIdx.x;
  const int wave = tid >> 6, lane = tid & 63;
  const int l16 = lane & 15, l4 = lane >> 4;

  const int flat = blockIdx.x;               // 0..511; 8 XCDs x 64, 4 heads/XCD
  const int xcd = flat & 7, i6 = flat >> 3;
  const int bn = xcd*4 + (i6 >> 4);
  const int q0 = (i6 & 15) * 128;
  const int b = bn >> 4, h = bn & (NHEAD-1);

  __shared__ __align__(16) bf16 KsF[2*128*64];   // 32 KB (2 bufs)
  __shared__ __align__(16) bf16 VtF[2*64*128];   // 32 KB (2 bufs)
  __shared__ __align__(16) bf16 PlF[8*16*64];    // 16 KB (per-wave 16 x 64, reused per half)

  const size_t hb = (size_t)bn * TT * DHEAD;
  const bf16* __restrict__ Kbase = Kg + hb;
  const bf16* __restrict__ Vbase = VTg + hb;

  bf16x8 qf[2];
#pragma unroll
  for (int kk = 0; kk < 2; ++kk)
    qf[kk] = *reinterpret_cast<const bf16x8*>(
        &Qg[hb + (size_t)(q0 + wave*16 + l16) * DHEAD + kk*32 + l4*8]);

  f32x4 o[4];
#pragma unroll
  for (int n = 0; n < 4; ++n) o[n] = 0.f;
  float mrun = -1e30f, lrun = 0.f;

  // staging via gload16: linear LDS dest (lane order), source pre-swizzled.
  // K pass p: row = p*64 + (tid>>3), store-slot = tid&7  -> global slot = store^(row&7)
  // V pass p: row = p*32 + (tid>>4), store-slot = tid&15 -> global slot = store^(row&7)
  const int krow0 = tid >> 3, kslot = tid & 7;
  const int vrow0 = tid >> 4, vslot = tid & 15;

#define ASTAGE(buf, tn) do {                                                              \
    {                                                                                     \
      int r0_ = krow0,      s0_ = (kslot ^ (r0_ & 7)) * 8;                                \
      int r1_ = 64 + krow0, s1_ = (kslot ^ (r1_ & 7)) * 8;                                \
      gload16(&Kbase[(size_t)((tn) + r0_) * DHEAD + s0_], &KsF[(buf)*8192        + wave*512]); \
      gload16(&Kbase[(size_t)((tn) + r1_) * DHEAD + s1_], &KsF[(buf)*8192 + 4096 + wave*512]); \
      int vr0_ = vrow0,      vs0_ = (vslot ^ (vr0_ & 7)) * 8;                             \
      int vr1_ = 32 + vrow0, vs1_ = (vslot ^ (vr1_ & 7)) * 8;                             \
      gload16(&Vbase[(size_t)vr0_ * TT + (tn) + vs0_], &VtF[(buf)*8192        + wave*512]);    \
      gload16(&Vbase[(size_t)vr1_ * TT + (tn) + vs1_], &VtF[(buf)*8192 + 4096 + wave*512]);    \
    }                                                                                     \
  } while (0)

  ASTAGE(0, 0);
  __syncthreads();                           // drains own vmcnt + barrier: buf0 ready

  bf16* PlW = &PlF[wave * 1024];             // 16 rows x 64 elems

  for (int t0 = 0; t0 < TT; t0 += KVB) {
    const int cur = (t0 >> 7) & 1;
    const bool more = (t0 + KVB < TT);
    if (more) ASTAGE(cur ^ 1, t0 + KVB);     // fills other buf; completes by the barrier below

    const int kbase = cur * 8192, vbase = cur * 8192;

    // S^T = K Q^T : lane holds S^T[kv = n*16 + l4*4 + j][q = l16], n = 0..7
    f32x4 s[8];
#pragma unroll
    for (int n = 0; n < 8; ++n) s[n] = 0.f;
    __builtin_amdgcn_s_setprio(1);
#pragma unroll
    for (int n = 0; n < 8; ++n) {
      bf16x8 kf0 = *reinterpret_cast<const bf16x8*>(
          &KsF[kbase + (n*16 + l16)*64 + ((l4    ) ^ (l16 & 7))*8]);
      bf16x8 kf1 = *reinterpret_cast<const bf16x8*>(
          &KsF[kbase + (n*16 + l16)*64 + ((4 + l4) ^ (l16 & 7))*8]);
      s[n] = __builtin_amdgcn_mfma_f32_16x16x32_bf16(kf0, qf[0], s[n], 0, 0, 0);
      s[n] = __builtin_amdgcn_mfma_f32_16x16x32_bf16(kf1, qf[1], s[n], 0, 0, 0);
    }
    __builtin_amdgcn_s_setprio(0);

    // --- online softmax (exp2 domain), defer-max THR=8; tree reductions ---
    float mx[8];
#pragma unroll
    for (int n = 0; n < 8; ++n)
      mx[n] = fmaxf(fmaxf(s[n][0], s[n][1]), fmaxf(s[n][2], s[n][3]));
    float m01 = fmaxf(mx[0], mx[1]), m23 = fmaxf(mx[2], mx[3]);
    float m45 = fmaxf(mx[4], mx[5]), m67 = fmaxf(mx[6], mx[7]);
    float pm = fmaxf(fmaxf(m01, m23), fmaxf(m45, m67));
    pm = fmaxf(pm, __shfl_xor(pm, 16, 64));
    pm = fmaxf(pm, __shfl_xor(pm, 32, 64));

    if (!__all(pm <= mrun + 8.f)) {
      float mn = fmaxf(mrun, pm);
      float corr = fast_exp2(mrun - mn);
      mrun = mn;
      lrun *= corr;
      float cj[4];
#pragma unroll
      for (int j = 0; j < 4; ++j)
        cj[j] = __shfl(corr, ((lane >> 4) << 2) + j, 64);
#pragma unroll
      for (int n = 0; n < 4; ++n)
#pragma unroll
        for (int j = 0; j < 4; ++j) o[n][j] *= cj[j];
    }

    float ps[4] = {0.f, 0.f, 0.f, 0.f};
#pragma unroll
    for (int hh = 0; hh < 2; ++hh) {
      // exp + pack + write P for this 64-kv half
#pragma unroll
      for (int n4 = 0; n4 < 4; ++n4) {
        const int n = hh*4 + n4;
        bf16x4 pk;
#pragma unroll
        for (int j = 0; j < 4; ++j) {
          float pv = fast_exp2(s[n][j] - mrun);
          ps[j] += pv;
          pk[j] = (__bf16)pv;
        }
        *reinterpret_cast<bf16x4*>(
            &PlW[l16*64 + ((2*n4 + (l4 >> 1)) ^ (l16 & 7))*8 + (l4 & 1)*4]) = pk;
      }
      // PV for this half
      bf16x8 pf[2];
#pragma unroll
      for (int kkl = 0; kkl < 2; ++kkl)
        pf[kkl] = *reinterpret_cast<const bf16x8*>(
            &PlW[l16*64 + ((4*kkl + l4) ^ (l16 & 7))*8]);
      __builtin_amdgcn_s_setprio(1);
#pragma unroll
      for (int n = 0; n < 4; ++n)
#pragma unroll
        for (int kkl = 0; kkl < 2; ++kkl) {
          const int kk = hh*2 + kkl;
          bf16x8 vf = *reinterpret_cast<const bf16x8*>(
              &VtF[vbase + (n*16 + l16)*128 + ((4*kk + l4) ^ (l16 & 7))*8]);
          o[n] = __builtin_amdgcn_mfma_f32_16x16x32_bf16(pf[kkl], vf, o[n], 0, 0, 0);
        }
      __builtin_amdgcn_s_setprio(0);
    }
    float psum = (ps[0] + ps[1]) + (ps[2] + ps[3]);
    psum += __shfl_xor(psum, 16, 64);
    psum += __shfl_xor(psum, 32, 64);
    lrun += psum;

    __syncthreads();                     // drains own stage loads (vmcnt 0) + barrier
  }
#undef ASTAGE

  // epilogue
  float linv = 1.0f / lrun;
  float lj[4];
#pragma unroll
  for (int j = 0; j < 4; ++j)
    lj[j] = __shfl(linv, ((lane >> 4) << 2) + j, 64);
#pragma unroll
  for (int j = 0; j < 4; ++j) {
    int gt = q0 + wave*16 + l4*4 + j;
#pragma unroll
    for (int n = 0; n < 4; ++n)
      Aout[((size_t)(b*TT + gt))*CC + h*DHEAD + n*16 + l16] = f2b(o[n][j] * lj[j]);
  }
}

extern "C" void kernel_launch(void* const* d_in, const int* in_sizes, int n_in,
                              void* d_out, int out_size, void* d_ws, size_t ws_size,
                              hipStream_t stream)
{
  const float* x     = (const float*)d_in[0];
  const float* Wqkv  = (const float*)d_in[1];
  const float* bqkv  = (const float*)d_in[2];
  const float* Wproj = (const float*)d_in[3];
  const float* bproj = (const float*)d_in[4];
  float* out = (float*)d_out;

  char* p = (char*)d_ws;
  bf16* Xb     = (bf16*)p;  p += (size_t)MM*CC*2;
  bf16* WqkvT  = (bf16*)p;  p += (size_t)3*CC*CC*2;
  bf16* WprojT = (bf16*)p;  p += (size_t)CC*CC*2;
  bf16* Qb     = (bf16*)p;  p += (size_t)MM*CC*2;
  bf16* Kb     = (bf16*)p;  p += (size_t)MM*CC*2;
  bf16* Vb     = (bf16*)p;  p += (size_t)MM*CC*2;   // holds V^T (B,N,D,T) directly
  bf16* Attn   = (bf16*)p;  p += (size_t)MM*CC*2;

  k_prep<<<5120, 256, 0, stream>>>(x, Xb, Wqkv, WqkvT, Wproj, WprojT);
  k_gemm_qkv<<<384, 512, 0, stream>>>(Xb, WqkvT, bqkv, Qb, Kb, Vb);
  k_attn<<<512, 512, 0, stream>>>(Qb, Kb, Vb, Attn);
  k_gemm_proj<<<256, 512, 0, stream>>>(Attn, WprojT, bproj, out);
}